// Round 1
// baseline (604.838 us; speedup 1.0000x reference)
//
#include <hip/hip_runtime.h>
#include <hip/hip_bf16.h>
#include <stdint.h>

typedef __bf16 bf16_t;
typedef __bf16 bf16x8 __attribute__((ext_vector_type(8)));
typedef float f32x4 __attribute__((ext_vector_type(4)));

#define SCALING 0.125f

// ws layout (byte offsets)
#define WS_XQ  (0u)         // [4096][1024] bf16 query
#define WS_W   (8u << 20)   // 4 x [1024][1024] bf16 (Wq,Wk,Wv,Wo)
#define WS_QH  (16u << 20)  // [32][2048][64] bf16  q*scale, head layout
#define WS_KH  (24u << 20)  // [32][2048][64] bf16
#define WS_VT  (32u << 20)  // [32][64][2048] bf16  (transposed V)
#define WS_X2  (40u << 20)  // [4096][1024] bf16  attention head outputs

// d_out offsets (float elements)
#define OFF_OUT 0
#define OFF_WEI 4194304
#define OFF_K   138412032
#define OFF_V   142606336

typedef const __attribute__((address_space(1))) void gvoid_t;
typedef __attribute__((address_space(3))) void lvoid_t;

__device__ inline void gload_lds16(const void* g, void* l) {
  __builtin_amdgcn_global_load_lds((gvoid_t*)g, (lvoid_t*)l, 16, 0, 0);
}

// ---------------- fp32 -> bf16 conversion ----------------
__global__ __launch_bounds__(256) void cvt_kernel(const float* __restrict__ s,
                                                  bf16_t* __restrict__ d, int n4) {
  int i = blockIdx.x * 256 + threadIdx.x;
  if (i < n4) {
    float4 v = ((const float4*)s)[i];
    union { bf16_t h[4]; uint2 u; } o;
    o.h[0] = (bf16_t)v.x; o.h[1] = (bf16_t)v.y;
    o.h[2] = (bf16_t)v.z; o.h[3] = (bf16_t)v.w;
    ((uint2*)d)[i] = o.u;
  }
}

__global__ __launch_bounds__(256) void cvtw_kernel(const float* __restrict__ w0,
                                                   const float* __restrict__ w1,
                                                   const float* __restrict__ w2,
                                                   const float* __restrict__ w3,
                                                   bf16_t* __restrict__ dst) {
  const float* src = blockIdx.y == 0 ? w0 : blockIdx.y == 1 ? w1 : blockIdx.y == 2 ? w2 : w3;
  bf16_t* d = dst + (size_t)blockIdx.y * 1048576;
  int i = blockIdx.x * 256 + threadIdx.x;  // grid.x = 1024 -> 262144 float4s
  float4 v = ((const float4*)src)[i];
  union { bf16_t h[4]; uint2 u; } o;
  o.h[0] = (bf16_t)v.x; o.h[1] = (bf16_t)v.y;
  o.h[2] = (bf16_t)v.z; o.h[3] = (bf16_t)v.w;
  ((uint2*)d)[i] = o.u;
}

// ---------------- NT GEMM:  C[i][j] = sum_k X[i][k] * W[j][k] + bias[j] ----------------
// 128x128 tile, BK=64, 4 waves (2x2), 16x16x32 bf16 MFMA, global_load_lds staging.
// mode 0: q proj  -> qh bf16 (scaled)
// mode 1: k proj  -> d_out k_new fp32 + kh bf16
// mode 2: v proj  -> d_out v_new fp32 + vT bf16 (transposed)
// mode 3: out proj-> d_out attn_output fp32
__global__ __launch_bounds__(256) void gemm_nt(
    const bf16_t* __restrict__ Xq, const bf16_t* __restrict__ X2,
    const bf16_t* __restrict__ Wall,
    const float* __restrict__ bq, const float* __restrict__ bk,
    const float* __restrict__ bv, const float* __restrict__ bo,
    float* __restrict__ dout,
    bf16_t* __restrict__ qh, bf16_t* __restrict__ kh, bf16_t* __restrict__ vT,
    int mode_base) {
  const int mode = mode_base + blockIdx.z;
  const bf16_t* __restrict__ X = (mode < 3) ? Xq : X2;
  const bf16_t* __restrict__ W = Wall + (size_t)mode * 1048576;
  const float* __restrict__ bias = (mode == 0) ? bq : (mode == 1) ? bk : (mode == 2) ? bv : bo;

  __shared__ alignas(16) bf16_t Alds[128 * 64];
  __shared__ alignas(16) bf16_t Blds[128 * 64];

  const int lane = threadIdx.x & 63;
  const int w = threadIdx.x >> 6;
  const int wr = w >> 1, wc = w & 1;
  const int m0 = blockIdx.y * 128, n0 = blockIdx.x * 128;

  f32x4 acc[4][4] = {};

  for (int kk = 0; kk < 1024; kk += 64) {
    __syncthreads();
    const int rb = w * 32;
#pragma unroll
    for (int i = 0; i < 4; ++i) {
      int r = rb + i * 8 + (lane >> 3);
      int c = (lane & 7) * 8;
      gload_lds16(X + (size_t)(m0 + r) * 1024 + kk + c, &Alds[(rb + i * 8) * 64]);
      gload_lds16(W + (size_t)(n0 + r) * 1024 + kk + c, &Blds[(rb + i * 8) * 64]);
    }
    __syncthreads();
#pragma unroll
    for (int kx = 0; kx < 2; ++kx) {
      bf16x8 af[4], bfr[4];
#pragma unroll
      for (int mi = 0; mi < 4; ++mi)
        af[mi] = *(const bf16x8*)&Alds[(wr * 64 + mi * 16 + (lane & 15)) * 64 + kx * 32 + (lane >> 4) * 8];
#pragma unroll
      for (int ni = 0; ni < 4; ++ni)
        bfr[ni] = *(const bf16x8*)&Blds[(wc * 64 + ni * 16 + (lane & 15)) * 64 + kx * 32 + (lane >> 4) * 8];
#pragma unroll
      for (int mi = 0; mi < 4; ++mi)
#pragma unroll
        for (int ni = 0; ni < 4; ++ni)
          acc[mi][ni] = __builtin_amdgcn_mfma_f32_16x16x32_bf16(af[mi], bfr[ni], acc[mi][ni], 0, 0, 0);
    }
  }

  // epilogue: C row i = m0+wr*64+mi*16+(lane>>4)*4+r, col j = n0+wc*64+ni*16+(lane&15)
#pragma unroll
  for (int mi = 0; mi < 4; ++mi) {
#pragma unroll
    for (int ni = 0; ni < 4; ++ni) {
#pragma unroll
      for (int r = 0; r < 4; ++r) {
        int i = m0 + wr * 64 + mi * 16 + (lane >> 4) * 4 + r;
        int j = n0 + wc * 64 + ni * 16 + (lane & 15);
        float v = acc[mi][ni][r] + bias[j];
        int t = i >> 1, b = i & 1, h = j >> 6, d = j & 63;
        int bh = b * 16 + h;
        if (mode == 0) {
          qh[(size_t)bh * 131072 + t * 64 + d] = (bf16_t)(v * SCALING);
        } else if (mode == 1) {
          dout[OFF_K + (size_t)i * 1024 + j] = v;
          kh[(size_t)bh * 131072 + t * 64 + d] = (bf16_t)v;
        } else if (mode == 2) {
          dout[OFF_V + (size_t)i * 1024 + j] = v;
          vT[(size_t)bh * 131072 + d * 2048 + t] = (bf16_t)v;
        } else {
          dout[OFF_OUT + (size_t)i * 1024 + j] = v;
        }
      }
    }
  }
}

// ---------------- fused attention ----------------
// Block: 512 threads (8 waves), handles one bh and 16 q-rows over all S=2048.
// Wave w owns the 256-col slab s in [w*256, w*256+256). All scores in registers.
__global__ __launch_bounds__(512) void attn_kernel(
    const bf16_t* __restrict__ qh, const bf16_t* __restrict__ kh,
    const bf16_t* __restrict__ vT,
    const float* __restrict__ amask, const uint8_t* __restrict__ kpm,
    float* __restrict__ wout, bf16_t* __restrict__ X2) {
  const int lane = threadIdx.x & 63;
  const int w = threadIdx.x >> 6;  // 0..7
  const int t0 = blockIdx.x * 16;
  const int bh = blockIdx.y;
  const int b = bh >> 4;

  __shared__ float wred[2][16][8];
  __shared__ float pbuf[8][16][64];

  const bf16_t* __restrict__ qbase = qh + (size_t)bh * 131072;
  const bf16_t* __restrict__ kbase = kh + (size_t)bh * 131072;
  const bf16_t* __restrict__ vbase = vT + (size_t)bh * 131072;
  float* __restrict__ wrow = wout + (size_t)bh * 4194304;

  // Q A-fragments (row = lane&15 -> t, k = kx*32 + (lane>>4)*8 + j)
  bf16x8 aq[2];
#pragma unroll
  for (int kx = 0; kx < 2; ++kx)
    aq[kx] = *(const bf16x8*)&qbase[(t0 + (lane & 15)) * 64 + kx * 32 + (lane >> 4) * 8];

  // ---- scores: QK^T + masks, kept in registers (C layout) ----
  f32x4 sc[16];
  const int s0w = w * 256;
#pragma unroll
  for (int st = 0; st < 16; ++st) {
    int s0 = s0w + st * 16;
    f32x4 acc = {0.f, 0.f, 0.f, 0.f};
#pragma unroll
    for (int kx = 0; kx < 2; ++kx) {
      bf16x8 bk_ = *(const bf16x8*)&kbase[(s0 + (lane & 15)) * 64 + kx * 32 + (lane >> 4) * 8];
      acc = __builtin_amdgcn_mfma_f32_16x16x32_bf16(aq[kx], bk_, acc, 0, 0, 0);
    }
    int s = s0 + (lane & 15);
    uint8_t kp = kpm[b * 2048 + s];
#pragma unroll
    for (int r = 0; r < 4; ++r) {
      float mv = amask[(size_t)(t0 + (lane >> 4) * 4 + r) * 2048 + s];
      float val = acc[r] + mv;
      acc[r] = kp ? -__builtin_inff() : val;
    }
    sc[st] = acc;
  }

  // ---- row max: lane-local -> 16-lane shfl -> cross-wave via LDS ----
  float m4[4] = {-__builtin_inff(), -__builtin_inff(), -__builtin_inff(), -__builtin_inff()};
#pragma unroll
  for (int st = 0; st < 16; ++st)
#pragma unroll
    for (int r = 0; r < 4; ++r) m4[r] = fmaxf(m4[r], sc[st][r]);
#pragma unroll
  for (int msk = 1; msk <= 8; msk <<= 1)
#pragma unroll
    for (int r = 0; r < 4; ++r) m4[r] = fmaxf(m4[r], __shfl_xor(m4[r], msk, 64));
  if ((lane & 15) == 0) {
#pragma unroll
    for (int r = 0; r < 4; ++r) wred[0][(lane >> 4) * 4 + r][w] = m4[r];
  }
  __syncthreads();
  float gm[4];
#pragma unroll
  for (int r = 0; r < 4; ++r) {
    int row = (lane >> 4) * 4 + r;
    float mm = wred[0][row][0];
#pragma unroll
    for (int ww = 1; ww < 8; ++ww) mm = fmaxf(mm, wred[0][row][ww]);
    gm[r] = mm;
  }

  // ---- exp + row sums ----
  float s4[4] = {0.f, 0.f, 0.f, 0.f};
#pragma unroll
  for (int st = 0; st < 16; ++st) {
#pragma unroll
    for (int r = 0; r < 4; ++r) {
      float e = __expf(sc[st][r] - gm[r]);
      sc[st][r] = e;
      s4[r] += e;
    }
  }
#pragma unroll
  for (int msk = 1; msk <= 8; msk <<= 1)
#pragma unroll
    for (int r = 0; r < 4; ++r) s4[r] += __shfl_xor(s4[r], msk, 64);
  if ((lane & 15) == 0) {
#pragma unroll
    for (int r = 0; r < 4; ++r) wred[1][(lane >> 4) * 4 + r][w] = s4[r];
  }
  __syncthreads();
  float rl[4];
#pragma unroll
  for (int r = 0; r < 4; ++r) {
    int row = (lane >> 4) * 4 + r;
    float ss = 0.f;
#pragma unroll
    for (int ww = 0; ww < 8; ++ww) ss += wred[1][row][ww];
    rl[r] = 1.0f / ss;
  }

  // ---- write normalized weights (fp32, the big 537MB output) ----
#pragma unroll
  for (int st = 0; st < 16; ++st) {
    int s = s0w + st * 16 + (lane & 15);
#pragma unroll
    for (int r = 0; r < 4; ++r) {
      float wv = sc[st][r] * rl[r];
      wrow[(size_t)(t0 + (lane >> 4) * 4 + r) * 2048 + s] = wv;
    }
  }
  asm volatile("s_waitcnt vmcnt(0)" ::: "memory");

  // ---- PV: read back own weights in A-fragment layout (L2-hot), MFMA with vT ----
  f32x4 po[4] = {};
#pragma unroll
  for (int c = 0; c < 8; ++c) {
    int sb = s0w + c * 32;
    const float* wp = &wrow[(size_t)(t0 + (lane & 15)) * 2048 + sb + (lane >> 4) * 8];
    float4 w0 = *(const float4*)wp;
    float4 w1 = *(const float4*)(wp + 4);
    bf16x8 pa;
    pa[0] = (bf16_t)w0.x; pa[1] = (bf16_t)w0.y; pa[2] = (bf16_t)w0.z; pa[3] = (bf16_t)w0.w;
    pa[4] = (bf16_t)w1.x; pa[5] = (bf16_t)w1.y; pa[6] = (bf16_t)w1.z; pa[7] = (bf16_t)w1.w;
#pragma unroll
    for (int dt = 0; dt < 4; ++dt) {
      bf16x8 bv_ = *(const bf16x8*)&vbase[(size_t)(dt * 16 + (lane & 15)) * 2048 + sb + (lane >> 4) * 8];
      po[dt] = __builtin_amdgcn_mfma_f32_16x16x32_bf16(pa, bv_, po[dt], 0, 0, 0);
    }
  }

  // ---- cross-wave reduce of PV partials, write X2 (bf16 head outputs) ----
#pragma unroll
  for (int dt = 0; dt < 4; ++dt)
#pragma unroll
    for (int r = 0; r < 4; ++r)
      pbuf[w][(lane >> 4) * 4 + r][dt * 16 + (lane & 15)] = po[dt][r];
  __syncthreads();
  int e0 = threadIdx.x * 2;
  int row = e0 >> 6, d = e0 & 63;
  float v0 = 0.f, v1 = 0.f;
#pragma unroll
  for (int ww = 0; ww < 8; ++ww) {
    v0 += pbuf[ww][row][d];
    v1 += pbuf[ww][row][d + 1];
  }
  int h = bh & 15;
  union { bf16_t hh[2]; uint32_t u; } pk;
  pk.hh[0] = (bf16_t)v0; pk.hh[1] = (bf16_t)v1;
  *(uint32_t*)&X2[(size_t)((t0 + row) * 2 + b) * 1024 + h * 64 + d] = pk.u;
}

// ---------------- launch ----------------
extern "C" void kernel_launch(void* const* d_in, const int* in_sizes, int n_in,
                              void* d_out, int out_size, void* d_ws, size_t ws_size,
                              hipStream_t stream) {
  (void)in_sizes; (void)n_in; (void)out_size; (void)ws_size;
  const float* query = (const float*)d_in[0];
  const uint8_t* kpm = (const uint8_t*)d_in[1];
  const float* amask = (const float*)d_in[2];
  const float* Wq = (const float*)d_in[3];
  const float* bq = (const float*)d_in[4];
  const float* Wk = (const float*)d_in[5];
  const float* bk = (const float*)d_in[6];
  const float* Wv = (const float*)d_in[7];
  const float* bv = (const float*)d_in[8];
  const float* Wo = (const float*)d_in[9];
  const float* bo = (const float*)d_in[10];
  float* dout = (float*)d_out;
  char* ws = (char*)d_ws;

  bf16_t* Xq = (bf16_t*)(ws + WS_XQ);
  bf16_t* Wbf = (bf16_t*)(ws + WS_W);
  bf16_t* qh = (bf16_t*)(ws + WS_QH);
  bf16_t* kh = (bf16_t*)(ws + WS_KH);
  bf16_t* vT = (bf16_t*)(ws + WS_VT);
  bf16_t* X2 = (bf16_t*)(ws + WS_X2);

  cvt_kernel<<<4096, 256, 0, stream>>>(query, Xq, 1048576);
  cvtw_kernel<<<dim3(1024, 4), 256, 0, stream>>>(Wq, Wk, Wv, Wo, Wbf);
  gemm_nt<<<dim3(8, 32, 3), 256, 0, stream>>>(Xq, X2, Wbf, bq, bk, bv, bo, dout, qh, kh, vT, 0);
  attn_kernel<<<dim3(128, 32), 512, 0, stream>>>(qh, kh, vT, amask, kpm, dout + OFF_WEI, X2);
  gemm_nt<<<dim3(8, 32, 1), 256, 0, stream>>>(Xq, X2, Wbf, bq, bk, bv, bo, dout, qh, kh, vT, 3);
}

// Round 3
// 480.695 us; speedup vs baseline: 1.2583x; 1.2583x over previous
//
#include <hip/hip_runtime.h>
#include <hip/hip_bf16.h>
#include <stdint.h>

typedef __bf16 bf16_t;
typedef __bf16 bf16x8 __attribute__((ext_vector_type(8)));
typedef float f32x4 __attribute__((ext_vector_type(4)));

#define SCALING 0.125f

// ws layout (byte offsets)
#define WS_XQ  (0u)         // [4096][1024] bf16 query
#define WS_W   (8u << 20)   // 4 x [1024][1024] bf16 (Wq,Wk,Wv,Wo)
#define WS_QH  (16u << 20)  // [32][2048][64] bf16  q*scale, head layout
#define WS_KH  (24u << 20)  // [32][2048][64] bf16
#define WS_VT  (32u << 20)  // [32][64][2048] bf16  (transposed V)
#define WS_X2  (40u << 20)  // [4096][1024] bf16  attention head outputs

// d_out offsets (float elements)
#define OFF_OUT 0
#define OFF_WEI 4194304
#define OFF_K   138412032
#define OFF_V   142606336

typedef const __attribute__((address_space(1))) void gvoid_t;
typedef __attribute__((address_space(3))) void lvoid_t;

__device__ inline void gload_lds16(const void* g, void* l) {
  __builtin_amdgcn_global_load_lds((gvoid_t*)g, (lvoid_t*)l, 16, 0, 0);
}

// ---------------- fp32 -> bf16 conversion ----------------
__global__ __launch_bounds__(256) void cvt_kernel(const float* __restrict__ s,
                                                  bf16_t* __restrict__ d, int n4) {
  int i = blockIdx.x * 256 + threadIdx.x;
  if (i < n4) {
    float4 v = ((const float4*)s)[i];
    union { bf16_t h[4]; uint2 u; } o;
    o.h[0] = (bf16_t)v.x; o.h[1] = (bf16_t)v.y;
    o.h[2] = (bf16_t)v.z; o.h[3] = (bf16_t)v.w;
    ((uint2*)d)[i] = o.u;
  }
}

__global__ __launch_bounds__(256) void cvtw_kernel(const float* __restrict__ w0,
                                                   const float* __restrict__ w1,
                                                   const float* __restrict__ w2,
                                                   const float* __restrict__ w3,
                                                   bf16_t* __restrict__ dst) {
  const float* src = blockIdx.y == 0 ? w0 : blockIdx.y == 1 ? w1 : blockIdx.y == 2 ? w2 : w3;
  bf16_t* d = dst + (size_t)blockIdx.y * 1048576;
  int i = blockIdx.x * 256 + threadIdx.x;  // grid.x = 1024 -> 262144 float4s
  float4 v = ((const float4*)src)[i];
  union { bf16_t h[4]; uint2 u; } o;
  o.h[0] = (bf16_t)v.x; o.h[1] = (bf16_t)v.y;
  o.h[2] = (bf16_t)v.z; o.h[3] = (bf16_t)v.w;
  ((uint2*)d)[i] = o.u;
}

// ---------------- NT GEMM:  C[i][j] = sum_k X[i][k] * W[j][k] + bias[j] ----------------
// 128x128 tile, BK=64, 4 waves (2x2), 16x16x32 bf16 MFMA, global_load_lds staging.
__global__ __launch_bounds__(256) void gemm_nt(
    const bf16_t* __restrict__ Xq, const bf16_t* __restrict__ X2,
    const bf16_t* __restrict__ Wall,
    const float* __restrict__ bq, const float* __restrict__ bk,
    const float* __restrict__ bv, const float* __restrict__ bo,
    float* __restrict__ dout,
    bf16_t* __restrict__ qh, bf16_t* __restrict__ kh, bf16_t* __restrict__ vT,
    int mode_base) {
  const int mode = mode_base + blockIdx.z;
  const bf16_t* __restrict__ X = (mode < 3) ? Xq : X2;
  const bf16_t* __restrict__ W = Wall + (size_t)mode * 1048576;
  const float* __restrict__ bias = (mode == 0) ? bq : (mode == 1) ? bk : (mode == 2) ? bv : bo;

  __shared__ alignas(16) bf16_t Alds[128 * 64];
  __shared__ alignas(16) bf16_t Blds[128 * 64];

  const int lane = threadIdx.x & 63;
  const int w = threadIdx.x >> 6;
  const int wr = w >> 1, wc = w & 1;
  const int m0 = blockIdx.y * 128, n0 = blockIdx.x * 128;

  f32x4 acc[4][4] = {};

  for (int kk = 0; kk < 1024; kk += 64) {
    __syncthreads();
    const int rb = w * 32;
#pragma unroll
    for (int i = 0; i < 4; ++i) {
      int r = rb + i * 8 + (lane >> 3);
      int c = (lane & 7) * 8;
      gload_lds16(X + (size_t)(m0 + r) * 1024 + kk + c, &Alds[(rb + i * 8) * 64]);
      gload_lds16(W + (size_t)(n0 + r) * 1024 + kk + c, &Blds[(rb + i * 8) * 64]);
    }
    __syncthreads();
#pragma unroll
    for (int kx = 0; kx < 2; ++kx) {
      bf16x8 af[4], bfr[4];
#pragma unroll
      for (int mi = 0; mi < 4; ++mi)
        af[mi] = *(const bf16x8*)&Alds[(wr * 64 + mi * 16 + (lane & 15)) * 64 + kx * 32 + (lane >> 4) * 8];
#pragma unroll
      for (int ni = 0; ni < 4; ++ni)
        bfr[ni] = *(const bf16x8*)&Blds[(wc * 64 + ni * 16 + (lane & 15)) * 64 + kx * 32 + (lane >> 4) * 8];
#pragma unroll
      for (int mi = 0; mi < 4; ++mi)
#pragma unroll
        for (int ni = 0; ni < 4; ++ni)
          acc[mi][ni] = __builtin_amdgcn_mfma_f32_16x16x32_bf16(af[mi], bfr[ni], acc[mi][ni], 0, 0, 0);
    }
  }

  // epilogue: C row i = m0+wr*64+mi*16+(lane>>4)*4+r, col j = n0+wc*64+ni*16+(lane&15)
#pragma unroll
  for (int mi = 0; mi < 4; ++mi) {
#pragma unroll
    for (int ni = 0; ni < 4; ++ni) {
#pragma unroll
      for (int r = 0; r < 4; ++r) {
        int i = m0 + wr * 64 + mi * 16 + (lane >> 4) * 4 + r;
        int j = n0 + wc * 64 + ni * 16 + (lane & 15);
        float v = acc[mi][ni][r] + bias[j];
        int t = i >> 1, b = i & 1, h = j >> 6, d = j & 63;
        int bh = b * 16 + h;
        if (mode == 0) {
          qh[(size_t)bh * 131072 + t * 64 + d] = (bf16_t)(v * SCALING);
        } else if (mode == 1) {
          dout[OFF_K + (size_t)i * 1024 + j] = v;
          kh[(size_t)bh * 131072 + t * 64 + d] = (bf16_t)v;
        } else if (mode == 2) {
          dout[OFF_V + (size_t)i * 1024 + j] = v;
          vT[(size_t)bh * 131072 + d * 2048 + t] = (bf16_t)v;
        } else {
          dout[OFF_OUT + (size_t)i * 1024 + j] = v;
        }
      }
    }
  }
}

// ---------------- fused attention (swapped-QK^T, sigma-permuted s-rows) ----------------
// Block: 512 threads (8 waves), one bh, 16 q-rows, all S=2048.
// Wave w owns s-slab [w*256, w*256+256).
// Swapped MFMA: D = mfma(K_frag, Q_frag) -> col = t (lane&15), row = s.
// K rows loaded with permutation sigma(st,p)=32*(st>>1)+8*(p>>2)+4*(st&1)+(p&3)
// so each lane's scores are exactly the PV B-fragment elements (no shuffles).
__global__ __launch_bounds__(512, 4) void attn_kernel(
    const bf16_t* __restrict__ qh, const bf16_t* __restrict__ kh,
    const bf16_t* __restrict__ vT,
    const float* __restrict__ amask, const uint8_t* __restrict__ kpm,
    float* __restrict__ wout, bf16_t* __restrict__ X2) {
  const int lane = threadIdx.x & 63;
  const int w = threadIdx.x >> 6;   // 0..7
  const int lt = lane & 15;         // t within tile (fixed per lane)
  const int g = lane >> 4;          // 0..3
  const int t0 = blockIdx.x * 16;
  const int bh = blockIdx.y;
  const int b = bh >> 4;

  __shared__ float wred[2][16][8];
  __shared__ float pbuf[8][16][68];  // +4 pad breaks bank aliasing

  const bf16_t* __restrict__ qbase = qh + (size_t)bh * 131072;
  const bf16_t* __restrict__ kbase = kh + (size_t)bh * 131072;
  const bf16_t* __restrict__ vbase = vT + (size_t)bh * 131072;
  float* __restrict__ wrow = wout + (size_t)bh * 4194304;
  const int s0w = w * 256;

  // Q as B-operand: lane&15 = t, k = g*8 + j
  bf16x8 aq[2];
#pragma unroll
  for (int kx = 0; kx < 2; ++kx)
    aq[kx] = *(const bf16x8*)&qbase[(t0 + lt) * 64 + kx * 32 + g * 8];

  // K fragment row for tile st: s = s0w + 32*(st>>1) + 8*(lt>>2) + 4*(st&1) + (lt&3)
  const int krow_base = 8 * (lt >> 2) + (lt & 3);

  // ---- scores ----
  f32x4 sc[16];
#pragma unroll
  for (int st = 0; st < 16; ++st) {
    const int sblk = s0w + 32 * (st >> 1);
    const int se = 4 * (st & 1);
    const int srow = sblk + se + krow_base;
    f32x4 acc = {0.f, 0.f, 0.f, 0.f};
#pragma unroll
    for (int kx = 0; kx < 2; ++kx) {
      bf16x8 kf = *(const bf16x8*)&kbase[(size_t)srow * 64 + kx * 32 + g * 8];
      acc = __builtin_amdgcn_mfma_f32_16x16x32_bf16(kf, aq[kx], acc, 0, 0, 0);
    }
    // lane holds rows s = sblk + se + 8*g + r, col t = t0 + lt
    const int sl = sblk + se + 8 * g;
    float4 mv = *(const float4*)&amask[(size_t)(t0 + lt) * 2048 + sl];
    uint32_t ku = *(const uint32_t*)&kpm[b * 2048 + sl];
#pragma unroll
    for (int r = 0; r < 4; ++r) {
      float m = (r == 0) ? mv.x : (r == 1) ? mv.y : (r == 2) ? mv.z : mv.w;
      float val = acc[r] + m;
      acc[r] = ((ku >> (8 * r)) & 0xff) ? -__builtin_inff() : val;
    }
    sc[st] = acc;
  }

  // ---- row max (t fixed per lane -> lane-local + 2 shuffles + cross-wave LDS) ----
  float m = -__builtin_inff();
#pragma unroll
  for (int st = 0; st < 16; ++st)
#pragma unroll
    for (int r = 0; r < 4; ++r) m = fmaxf(m, sc[st][r]);
  m = fmaxf(m, __shfl_xor(m, 16, 64));
  m = fmaxf(m, __shfl_xor(m, 32, 64));
  if (lane < 16) wred[0][lane][w] = m;
  __syncthreads();
  float gm = wred[0][lt][0];
#pragma unroll
  for (int ww = 1; ww < 8; ++ww) gm = fmaxf(gm, wred[0][lt][ww]);

  // ---- exp + row sum ----
  float ssum = 0.f;
#pragma unroll
  for (int st = 0; st < 16; ++st) {
#pragma unroll
    for (int r = 0; r < 4; ++r) {
      float e = __expf(sc[st][r] - gm);
      sc[st][r] = e;
      ssum += e;
    }
  }
  ssum += __shfl_xor(ssum, 16, 64);
  ssum += __shfl_xor(ssum, 32, 64);
  if (lane < 16) wred[1][lane][w] = ssum;
  __syncthreads();
  float ss = 0.f;
#pragma unroll
  for (int ww = 0; ww < 8; ++ww) ss += wred[1][lt][ww];
  const float rl = 1.0f / ss;

  // ---- normalize, write weights (f32x4, nontemporal), build P fragments, PV ----
  f32x4 po[4] = {};
#pragma unroll
  for (int kx = 0; kx < 8; ++kx) {
    bf16x8 pa;
#pragma unroll
    for (int e = 0; e < 2; ++e) {
      f32x4 wv = sc[2 * kx + e] * rl;
      const int sl = s0w + 32 * kx + 4 * e + 8 * g;
      __builtin_nontemporal_store(wv, (f32x4*)&wrow[(size_t)(t0 + lt) * 2048 + sl]);
#pragma unroll
      for (int r = 0; r < 4; ++r) pa[4 * e + r] = (bf16_t)wv[r];
    }
#pragma unroll
    for (int dt = 0; dt < 4; ++dt) {
      bf16x8 vf = *(const bf16x8*)&vbase[(size_t)(dt * 16 + lt) * 2048 + s0w + kx * 32 + g * 8];
      po[dt] = __builtin_amdgcn_mfma_f32_16x16x32_bf16(vf, pa, po[dt], 0, 0, 0);
    }
  }

  // ---- cross-wave reduce of PV partials (O^T layout: row=d, col=t) ----
#pragma unroll
  for (int dt = 0; dt < 4; ++dt) {
    f32x4 v = po[dt];
    *(f32x4*)&pbuf[w][lt][dt * 16 + 4 * g] = v;
  }
  __syncthreads();
  int e0 = threadIdx.x * 2;
  int row = e0 >> 6, d = e0 & 63;
  float v0 = 0.f, v1 = 0.f;
#pragma unroll
  for (int ww = 0; ww < 8; ++ww) {
    v0 += pbuf[ww][row][d];
    v1 += pbuf[ww][row][d + 1];
  }
  int h = bh & 15;
  union { bf16_t hh[2]; uint32_t u; } pk;
  pk.hh[0] = (bf16_t)v0; pk.hh[1] = (bf16_t)v1;
  *(uint32_t*)&X2[(size_t)((t0 + row) * 2 + b) * 1024 + h * 64 + d] = pk.u;
}

// ---------------- launch ----------------
extern "C" void kernel_launch(void* const* d_in, const int* in_sizes, int n_in,
                              void* d_out, int out_size, void* d_ws, size_t ws_size,
                              hipStream_t stream) {
  (void)in_sizes; (void)n_in; (void)out_size; (void)ws_size;
  const float* query = (const float*)d_in[0];
  const uint8_t* kpm = (const uint8_t*)d_in[1];
  const float* amask = (const float*)d_in[2];
  const float* Wq = (const float*)d_in[3];
  const float* bq = (const float*)d_in[4];
  const float* Wk = (const float*)d_in[5];
  const float* bk = (const float*)d_in[6];
  const float* Wv = (const float*)d_in[7];
  const float* bv = (const float*)d_in[8];
  const float* Wo = (const float*)d_in[9];
  const float* bo = (const float*)d_in[10];
  float* dout = (float*)d_out;
  char* ws = (char*)d_ws;

  bf16_t* Xq = (bf16_t*)(ws + WS_XQ);
  bf16_t* Wbf = (bf16_t*)(ws + WS_W);
  bf16_t* qh = (bf16_t*)(ws + WS_QH);
  bf16_t* kh = (bf16_t*)(ws + WS_KH);
  bf16_t* vT = (bf16_t*)(ws + WS_VT);
  bf16_t* X2 = (bf16_t*)(ws + WS_X2);

  cvt_kernel<<<4096, 256, 0, stream>>>(query, Xq, 1048576);
  cvtw_kernel<<<dim3(1024, 4), 256, 0, stream>>>(Wq, Wk, Wv, Wo, Wbf);
  gemm_nt<<<dim3(8, 32, 3), 256, 0, stream>>>(Xq, X2, Wbf, bq, bk, bv, bo, dout, qh, kh, vT, 0);
  attn_kernel<<<dim3(128, 32), 512, 0, stream>>>(qh, kh, vT, amask, kpm, dout + OFF_WEI, X2);
  gemm_nt<<<dim3(8, 32, 1), 256, 0, stream>>>(Xq, X2, Wbf, bq, bk, bv, bo, dout, qh, kh, vT, 3);
}